// Round 6
// baseline (934.004 us; speedup 1.0000x reference)
//
#include <hip/hip_runtime.h>

#define NU 50000
#define NI 50000
#define NN 100000
#define NE 1600000
#define NP 200000
#define DIM 128
#define HID 64

typedef unsigned short bf16_t;

__device__ __forceinline__ float bf2f(unsigned short u) {
  union { unsigned int i; float f; } c; c.i = ((unsigned int)u) << 16; return c.f;
}
__device__ __forceinline__ unsigned short f2bf(float f) {
  union { float f; unsigned int i; } c; c.f = f;
  unsigned int i = c.i;
  i += 0x7fffu + ((i >> 16) & 1u);   // RNE
  return (unsigned short)(i >> 16);
}
// index load handling both int32 and int64 storage (values < 2^31, nonneg)
__device__ __forceinline__ int geti(const void* p, int i, bool i64) {
  return i64 ? (int)((const long long*)p)[i] : ((const int*)p)[i];
}

// ---------------- dtype probes ----------------
// flag[0]: 1 if float inputs are fp32 (bf16-misread shows huge finite values), else 0
// flag[1]: 1 if int inputs are int64 (odd int32 words all zero), else 0
__global__ __launch_bounds__(64) void k_detect(const bf16_t* __restrict__ uf,
                                               const int* __restrict__ ei,
                                               int* __restrict__ flag) {
  int lane = threadIdx.x;
  float m = 0.f;
  for (int i = lane; i < 4096; i += 64) {
    float v = fabsf(bf2f(uf[i]));
    if (v < 3e38f) m = fmaxf(m, v);   // filters inf/NaN
  }
  int cnt = 0;
  for (int i = lane; i < 4096; i += 64) {
    if (ei[2 * i + 1] == 0) cnt++;    // high words of int64 are all 0
  }
  for (int off = 32; off > 0; off >>= 1) {
    m = fmaxf(m, __shfl_xor(m, off));
    cnt += __shfl_xor(cnt, off);
  }
  if (lane == 0) {
    flag[0] = (m > 100.f) ? 1 : 0;
    flag[1] = (cnt > 2048) ? 1 : 0;
  }
}

// ---------------- degrees ----------------
__global__ __launch_bounds__(256) void k_degrees(const void* __restrict__ src,
                                                 const void* __restrict__ dst,
                                                 const int* __restrict__ flag,
                                                 int* __restrict__ dout,
                                                 int* __restrict__ din) {
  const bool i64 = (flag[1] != 0);
  int e = blockIdx.x * 256 + threadIdx.x;
  if (e < NE) {
    atomicAdd(&dout[geti(src, e, i64)], 1);
    atomicAdd(&din[geti(dst, e, i64)], 1);
  }
}

// ---------------- norms ----------------
__global__ __launch_bounds__(256) void k_norms(const int* __restrict__ dout,
                                               const int* __restrict__ din,
                                               float* __restrict__ onorm,
                                               float* __restrict__ inorm) {
  int n = blockIdx.x * 256 + threadIdx.x;
  if (n < NN) {
    int o = dout[n] > 1 ? dout[n] : 1;
    int in_ = din[n] > 1 ? din[n] : 1;
    onorm[n] = rsqrtf((float)o);
    inorm[n] = rsqrtf((float)in_);
  }
}

// ---------------- scan (1024 elems per block) ----------------
__global__ __launch_bounds__(256) void k_scan1(const int* __restrict__ in,
                                               int* __restrict__ bsums, int n) {
  __shared__ int sh[256];
  int t = threadIdx.x;
  int base = blockIdx.x * 1024 + t * 4;
  int s = 0;
#pragma unroll
  for (int i = 0; i < 4; ++i)
    if (base + i < n) s += in[base + i];
  sh[t] = s;
  __syncthreads();
  for (int off = 128; off > 0; off >>= 1) {
    if (t < off) sh[t] += sh[t + off];
    __syncthreads();
  }
  if (t == 0) bsums[blockIdx.x] = sh[0];
}

__global__ __launch_bounds__(128) void k_scan2(const int* __restrict__ bsums,
                                               int* __restrict__ boffs, int nb) {
  __shared__ int sh[128];
  int t = threadIdx.x;
  int own = (t < nb) ? bsums[t] : 0;
  sh[t] = own;
  __syncthreads();
  for (int off = 1; off < 128; off <<= 1) {
    int add = (t >= off) ? sh[t - off] : 0;
    __syncthreads();
    sh[t] += add;
    __syncthreads();
  }
  if (t < nb) boffs[t] = sh[t] - own;   // exclusive
}

__global__ __launch_bounds__(256) void k_scan3(const int* __restrict__ in,
                                               const int* __restrict__ boffs,
                                               int* __restrict__ row_ptr,
                                               int* __restrict__ cursor, int n) {
  __shared__ int sh[256];
  int t = threadIdx.x;
  int base = blockIdx.x * 1024 + t * 4;
  int v[4];
  int s = 0;
#pragma unroll
  for (int i = 0; i < 4; ++i) {
    v[i] = (base + i < n) ? in[base + i] : 0;
    s += v[i];
  }
  sh[t] = s;
  __syncthreads();
  for (int off = 1; off < 256; off <<= 1) {
    int add = (t >= off) ? sh[t - off] : 0;
    __syncthreads();
    sh[t] += add;
    __syncthreads();
  }
  int excl = boffs[blockIdx.x] + sh[t] - s;
#pragma unroll
  for (int i = 0; i < 4; ++i) {
    if (base + i < n) {
      row_ptr[base + i] = excl;
      cursor[base + i] = excl;
      excl += v[i];
    }
  }
  if (blockIdx.x == 0 && t == 0) row_ptr[n] = NE;
}

// ---------------- CSR fill ----------------
__global__ __launch_bounds__(256) void k_fill(const void* __restrict__ src,
                                              const void* __restrict__ dst,
                                              const int* __restrict__ flag,
                                              int* __restrict__ cursor,
                                              int* __restrict__ csr_src) {
  const bool i64 = (flag[1] != 0);
  int e = blockIdx.x * 256 + threadIdx.x;
  if (e < NE) {
    int d = geti(dst, e, i64);
    int slot = atomicAdd(&cursor[d], 1);
    csr_src[slot] = geti(src, e, i64);
  }
}

// ---------------- feature embedding: relu(X @ W + b) -> fp32 ----------------
__global__ __launch_bounds__(256) void k_embed(const void* __restrict__ featv,
                                               const void* __restrict__ Wv,
                                               const void* __restrict__ biasv,
                                               const int* __restrict__ flag,
                                               float* __restrict__ out, int rows) {
  __shared__ float Ws[DIM * HID];  // 32 KB
  __shared__ float bs[HID];
  const bool f32 = (flag[0] != 0);
  int t = threadIdx.x;
  if (f32) {
    const float* W = (const float*)Wv;
    for (int i = t; i < DIM * HID; i += 256) Ws[i] = W[i];
    if (t < HID) bs[t] = ((const float*)biasv)[t];
  } else {
    const bf16_t* W = (const bf16_t*)Wv;
    for (int i = t; i < DIM * HID; i += 256) Ws[i] = bf2f(W[i]);
    if (t < HID) bs[t] = bf2f(((const bf16_t*)biasv)[t]);
  }
  __syncthreads();
  int rl = t >> 4;  // 0..15 local row
  int jq = t & 15;  // 0..15 col quad
  for (int rbase = blockIdx.x * 16; rbase < rows; rbase += gridDim.x * 16) {
    int row = rbase + rl;
    if (row >= rows) continue;
    float a0 = 0.f, a1 = 0.f, a2 = 0.f, a3 = 0.f;
    if (f32) {
      const float* fr = (const float*)featv + (size_t)row * DIM;
      for (int k0 = 0; k0 < DIM; k0 += 4) {
        float4 f4 = *(const float4*)(fr + k0);
        float fk[4] = {f4.x, f4.y, f4.z, f4.w};
#pragma unroll
        for (int kk = 0; kk < 4; ++kk) {
          const float* wr = &Ws[(k0 + kk) * HID + jq * 4];
          a0 += fk[kk] * wr[0];
          a1 += fk[kk] * wr[1];
          a2 += fk[kk] * wr[2];
          a3 += fk[kk] * wr[3];
        }
      }
    } else {
      const bf16_t* fr = (const bf16_t*)featv + (size_t)row * DIM;
      for (int k0 = 0; k0 < DIM; k0 += 8) {
        uint4 u = *(const uint4*)(fr + k0);
        unsigned int w[4] = {u.x, u.y, u.z, u.w};
#pragma unroll
        for (int kk = 0; kk < 8; ++kk) {
          unsigned short us = (unsigned short)((w[kk >> 1] >> ((kk & 1) * 16)) & 0xffffu);
          float fk = bf2f(us);
          const float* wr = &Ws[(k0 + kk) * HID + jq * 4];
          a0 += fk * wr[0];
          a1 += fk * wr[1];
          a2 += fk * wr[2];
          a3 += fk * wr[3];
        }
      }
    }
    float4 r;
    r.x = fmaxf(a0 + bs[jq * 4 + 0], 0.f);
    r.y = fmaxf(a1 + bs[jq * 4 + 1], 0.f);
    r.z = fmaxf(a2 + bs[jq * 4 + 2], 0.f);
    r.w = fmaxf(a3 + bs[jq * 4 + 3], 0.f);
    *(float4*)&out[(size_t)row * HID + jq * 4] = r;
  }
}

// ---------------- GCN gather layer 1 (pull, fp32 in, bf16 out, fp32 accumulate)
__global__ __launch_bounds__(256) void k_gather1(const float* __restrict__ emb,
                                                 const float* __restrict__ onorm,
                                                 const float* __restrict__ inorm,
                                                 const int* __restrict__ row_ptr,
                                                 const int* __restrict__ csr_src,
                                                 bf16_t* __restrict__ out) {
  int wave = (blockIdx.x * 256 + threadIdx.x) >> 6;
  int lane = threadIdx.x & 63;
  if (wave >= NN) return;
  int beg = row_ptr[wave];
  int end = row_ptr[wave + 1];
  float acc = 0.f;
  for (int e = beg; e < end; ++e) {
    int s = csr_src[e];
    acc += emb[(size_t)s * HID + lane] * onorm[s];
  }
  out[(size_t)wave * HID + lane] = f2bf(acc * inorm[wave]);
}

// ---------------- GCN gather layer 2 fused with combine + side-add; IN-PLACE on fp32 emb0
// (safe: emb0 is only ever read at this thread's own offset; gathers read e1)
__global__ __launch_bounds__(256) void k_gather2c(float* __restrict__ emb0,   // == final out region
                                                  const bf16_t* __restrict__ e1,
                                                  const void* __restrict__ sidev,
                                                  const int* __restrict__ flag,
                                                  const float* __restrict__ onorm,
                                                  const float* __restrict__ inorm,
                                                  const int* __restrict__ row_ptr,
                                                  const int* __restrict__ csr_src) {
  int wave = (blockIdx.x * 256 + threadIdx.x) >> 6;
  int lane = threadIdx.x & 63;
  if (wave >= NN) return;
  int beg = row_ptr[wave];
  int end = row_ptr[wave + 1];
  float acc = 0.f;
  for (int e = beg; e < end; ++e) {
    int s = csr_src[e];
    acc += bf2f(e1[(size_t)s * HID + lane]) * onorm[s];
  }
  size_t off = (size_t)wave * HID + lane;
  float v = emb0[off] + 0.5f * bf2f(e1[off]) + (1.f / 3.f) * acc * inorm[wave];
  if (wave >= NU) {
    size_t soff = (size_t)(wave - NU) * HID + lane;
    v += (flag[0] != 0) ? ((const float*)sidev)[soff] : bf2f(((const bf16_t*)sidev)[soff]);
  }
  emb0[off] = v;
}

// ---------------- decode: logits = elu([u,z,T] @ W1 + b1) @ W2 (fp32 out) ----------------
__global__ __launch_bounds__(256) void k_decode(const float* __restrict__ emb,
                                                const void* __restrict__ W1v,
                                                const void* __restrict__ b1v,
                                                const void* __restrict__ W2v,
                                                const void* __restrict__ Tfv,
                                                const void* __restrict__ Tcfv,
                                                const int* __restrict__ flag,
                                                const void* __restrict__ userId,
                                                const void* __restrict__ posId,
                                                const void* __restrict__ negId,
                                                float* __restrict__ out_lf,
                                                float* __restrict__ out_lcf) {
  __shared__ float W1s[129 * HID];  // 33 KB
  __shared__ float b1s[HID];
  __shared__ float W2s[HID];
  const bool f32 = (flag[0] != 0);
  const bool i64 = (flag[1] != 0);
  int t = threadIdx.x;
  if (f32) {
    const float* W1 = (const float*)W1v;
    for (int i = t; i < 129 * HID; i += 256) W1s[i] = W1[i];
    if (t < HID) {
      b1s[t] = ((const float*)b1v)[t];
      W2s[t] = ((const float*)W2v)[t];
    }
  } else {
    const bf16_t* W1 = (const bf16_t*)W1v;
    for (int i = t; i < 129 * HID; i += 256) W1s[i] = bf2f(W1[i]);
    if (t < HID) {
      b1s[t] = bf2f(((const bf16_t*)b1v)[t]);
      W2s[t] = bf2f(((const bf16_t*)W2v)[t]);
    }
  }
  __syncthreads();
  int prl = t >> 1;
  int half = t & 1;
  int pr = blockIdx.x * 128 + prl;
  if (pr >= 2 * NP) return;
  int pid = pr < NP ? pr : pr - NP;
  int uid = geti(userId, pid, i64);
  int iid = (pr < NP) ? geti(posId, pid, i64) : geti(negId, pid, i64);
  const float* ur = emb + (size_t)uid * HID;
  const float* ir = emb + (size_t)(NU + iid) * HID;
  int jb = half * 32;
  float acc[32];
#pragma unroll
  for (int j = 0; j < 32; ++j) acc[j] = b1s[jb + j];
  for (int pass = 0; pass < 2; ++pass) {
    const float* zr = pass ? ir : ur;
    const float* Wbase = &W1s[pass * 64 * HID];
    for (int k0 = 0; k0 < HID; k0 += 4) {
      float4 z4 = *(const float4*)(zr + k0);
      float zk[4] = {z4.x, z4.y, z4.z, z4.w};
#pragma unroll
      for (int kk = 0; kk < 4; ++kk) {
        const float* wr = &Wbase[(size_t)(k0 + kk) * HID + jb];
#pragma unroll
        for (int q = 0; q < 8; ++q) {
          float4 w = *(const float4*)(wr + q * 4);
          acc[q * 4 + 0] += zk[kk] * w.x;
          acc[q * 4 + 1] += zk[kk] * w.y;
          acc[q * 4 + 2] += zk[kk] * w.z;
          acc[q * 4 + 3] += zk[kk] * w.w;
        }
      }
    }
  }
  float tf, tcf;
  if (f32) {
    tf = ((const float*)Tfv)[pr];
    tcf = ((const float*)Tcfv)[pr];
  } else {
    tf = bf2f(((const bf16_t*)Tfv)[pr]);
    tcf = bf2f(((const bf16_t*)Tcfv)[pr]);
  }
  const float* wlast = &W1s[128 * HID + jb];
  float sf = 0.f, scf = 0.f;
#pragma unroll
  for (int j = 0; j < 32; ++j) {
    float wl = wlast[j];
    float w2 = W2s[jb + j];
    float bfv = acc[j] + tf * wl;
    float bcv = acc[j] + tcf * wl;
    float hf = bfv > 0.f ? bfv : (expf(bfv) - 1.f);
    float hc = bcv > 0.f ? bcv : (expf(bcv) - 1.f);
    sf += hf * w2;
    scf += hc * w2;
  }
  sf += __shfl_xor(sf, 1);
  scf += __shfl_xor(scf, 1);
  if (half == 0) {
    out_lf[pr] = sf;
    out_lcf[pr] = scf;
  }
}

extern "C" void kernel_launch(void* const* d_in, const int* in_sizes, int n_in,
                              void* d_out, int out_size, void* d_ws, size_t ws_size,
                              hipStream_t stream) {
  (void)in_sizes; (void)n_in; (void)out_size;
  const void* user_f = d_in[0];
  const void* item_f = d_in[1];
  const void* side   = d_in[2];
  const void* Tf     = d_in[3];
  const void* Tcf    = d_in[4];
  const void* Wu     = d_in[5];
  const void* bu     = d_in[6];
  const void* Wi     = d_in[7];
  const void* bi     = d_in[8];
  const void* W1     = d_in[9];
  const void* b1     = d_in[10];
  const void* W2     = d_in[11];
  const void* esrc   = d_in[12];
  const void* edst   = d_in[13];
  const void* userId = d_in[14];
  const void* posId  = d_in[15];
  const void* negId  = d_in[16];

  // compact workspace layout — total 21,601,280 B (known to fit)
  const size_t WS_NEEDED = 21601280;
  if (ws_size < WS_NEEDED) return;

  char* ws = (char*)d_ws;
  int*   deg_out = (int*)(ws + 0);          // 400000 B
  int*   deg_in  = (int*)(ws + 400000);     // 400000 B
  float* onorm   = (float*)(ws + 800000);   // 400000 B
  float* inorm   = (float*)(ws + 1200000);  // 400000 B
  int*   row_ptr = (int*)(ws + 1600000);    // 100001 ints (padded to 400128)
  int*   cursor  = (int*)(ws + 2000128);    // 400000 B
  int*   bsums   = (int*)(ws + 2400128);    // 512 B
  int*   boffs   = (int*)(ws + 2400640);    // 512 B
  int*   flag    = (int*)(ws + 2401152);    // 128 B (flag[0]=f32, flag[1]=i64)
  int*   csr_src = (int*)(ws + 2401280);    // 6,400,000 B
  bf16_t* e1     = (bf16_t*)(ws + 8801280); // 12,800,000 B -> ends 21,601,280

  float* out     = (float*)d_out;
  float* emb0    = out;                        // fp32 embeddings staged in output region
  float* out_lf  = out + (size_t)NN * HID;     // 6,400,000 floats in
  float* out_lcf = out_lf + 2 * NP;            // 6,800,000

  hipMemsetAsync(deg_out, 0, 800000, stream);  // deg_out + deg_in (contiguous)

  k_detect<<<1, 64, 0, stream>>>((const bf16_t*)user_f, (const int*)esrc, flag);
  k_degrees<<<(NE + 255) / 256, 256, 0, stream>>>(esrc, edst, flag, deg_out, deg_in);
  k_norms<<<(NN + 255) / 256, 256, 0, stream>>>(deg_out, deg_in, onorm, inorm);
  k_scan1<<<98, 256, 0, stream>>>(deg_in, bsums, NN);
  k_scan2<<<1, 128, 0, stream>>>(bsums, boffs, 98);
  k_scan3<<<98, 256, 0, stream>>>(deg_in, boffs, row_ptr, cursor, NN);
  k_fill<<<(NE + 255) / 256, 256, 0, stream>>>(esrc, edst, flag, cursor, csr_src);
  k_embed<<<256, 256, 0, stream>>>(user_f, Wu, bu, flag, emb0, NU);
  k_embed<<<256, 256, 0, stream>>>(item_f, Wi, bi, flag, emb0 + (size_t)NU * HID, NI);
  k_gather1<<<NN / 4, 256, 0, stream>>>(emb0, onorm, inorm, row_ptr, csr_src, e1);
  k_gather2c<<<NN / 4, 256, 0, stream>>>(emb0, e1, side, flag, onorm, inorm, row_ptr, csr_src);
  k_decode<<<(2 * NP) / 128, 256, 0, stream>>>(emb0, W1, b1, W2, Tf, Tcf, flag,
                                               userId, posId, negId, out_lf, out_lcf);
}

// Round 7
// 745.658 us; speedup vs baseline: 1.2526x; 1.2526x over previous
//
#include <hip/hip_runtime.h>

#define NU 50000
#define NI 50000
#define NN 100000
#define NE 1600000
#define NP 200000
#define DIM 128
#define HID 64

typedef unsigned short bf16_t;

__device__ __forceinline__ float bf2f(unsigned short u) {
  union { unsigned int i; float f; } c; c.i = ((unsigned int)u) << 16; return c.f;
}
__device__ __forceinline__ unsigned short f2bf(float f) {
  union { float f; unsigned int i; } c; c.f = f;
  unsigned int i = c.i;
  i += 0x7fffu + ((i >> 16) & 1u);   // RNE
  return (unsigned short)(i >> 16);
}
__device__ __forceinline__ int geti(const void* p, int i, bool i64) {
  return i64 ? (int)((const long long*)p)[i] : ((const int*)p)[i];
}

// ---------------- dtype probes ----------------
__global__ __launch_bounds__(64) void k_detect(const bf16_t* __restrict__ uf,
                                               const int* __restrict__ ei,
                                               int* __restrict__ flag) {
  int lane = threadIdx.x;
  float m = 0.f;
  for (int i = lane; i < 4096; i += 64) {
    float v = fabsf(bf2f(uf[i]));
    if (v < 3e38f) m = fmaxf(m, v);
  }
  int cnt = 0;
  for (int i = lane; i < 4096; i += 64) {
    if (ei[2 * i + 1] == 0) cnt++;
  }
  for (int off = 32; off > 0; off >>= 1) {
    m = fmaxf(m, __shfl_xor(m, off));
    cnt += __shfl_xor(cnt, off);
  }
  if (lane == 0) {
    flag[0] = (m > 100.f) ? 1 : 0;   // fp32 floats
    flag[1] = (cnt > 2048) ? 1 : 0;  // int64 ints
  }
}

// ---------------- degrees ----------------
__global__ __launch_bounds__(256) void k_degrees(const void* __restrict__ src,
                                                 const void* __restrict__ dst,
                                                 const int* __restrict__ flag,
                                                 int* __restrict__ dout,
                                                 int* __restrict__ din) {
  const bool i64 = (flag[1] != 0);
  int e = blockIdx.x * 256 + threadIdx.x;
  if (e < NE) {
    atomicAdd(&dout[geti(src, e, i64)], 1);
    atomicAdd(&din[geti(dst, e, i64)], 1);
  }
}

// ---------------- norms ----------------
__global__ __launch_bounds__(256) void k_norms(const int* __restrict__ dout,
                                               const int* __restrict__ din,
                                               float* __restrict__ onorm,
                                               float* __restrict__ inorm) {
  int n = blockIdx.x * 256 + threadIdx.x;
  if (n < NN) {
    int o = dout[n] > 1 ? dout[n] : 1;
    int in_ = din[n] > 1 ? din[n] : 1;
    onorm[n] = rsqrtf((float)o);
    inorm[n] = rsqrtf((float)in_);
  }
}

// ---------------- scan ----------------
__global__ __launch_bounds__(256) void k_scan1(const int* __restrict__ in,
                                               int* __restrict__ bsums, int n) {
  __shared__ int sh[256];
  int t = threadIdx.x;
  int base = blockIdx.x * 1024 + t * 4;
  int s = 0;
#pragma unroll
  for (int i = 0; i < 4; ++i)
    if (base + i < n) s += in[base + i];
  sh[t] = s;
  __syncthreads();
  for (int off = 128; off > 0; off >>= 1) {
    if (t < off) sh[t] += sh[t + off];
    __syncthreads();
  }
  if (t == 0) bsums[blockIdx.x] = sh[0];
}

__global__ __launch_bounds__(128) void k_scan2(const int* __restrict__ bsums,
                                               int* __restrict__ boffs, int nb) {
  __shared__ int sh[128];
  int t = threadIdx.x;
  int own = (t < nb) ? bsums[t] : 0;
  sh[t] = own;
  __syncthreads();
  for (int off = 1; off < 128; off <<= 1) {
    int add = (t >= off) ? sh[t - off] : 0;
    __syncthreads();
    sh[t] += add;
    __syncthreads();
  }
  if (t < nb) boffs[t] = sh[t] - own;
}

__global__ __launch_bounds__(256) void k_scan3(const int* __restrict__ in,
                                               const int* __restrict__ boffs,
                                               int* __restrict__ row_ptr,
                                               int* __restrict__ cursor, int n) {
  __shared__ int sh[256];
  int t = threadIdx.x;
  int base = blockIdx.x * 1024 + t * 4;
  int v[4];
  int s = 0;
#pragma unroll
  for (int i = 0; i < 4; ++i) {
    v[i] = (base + i < n) ? in[base + i] : 0;
    s += v[i];
  }
  sh[t] = s;
  __syncthreads();
  for (int off = 1; off < 256; off <<= 1) {
    int add = (t >= off) ? sh[t - off] : 0;
    __syncthreads();
    sh[t] += add;
    __syncthreads();
  }
  int excl = boffs[blockIdx.x] + sh[t] - s;
#pragma unroll
  for (int i = 0; i < 4; ++i) {
    if (base + i < n) {
      row_ptr[base + i] = excl;
      cursor[base + i] = excl;
      excl += v[i];
    }
  }
  if (blockIdx.x == 0 && t == 0) row_ptr[n] = NE;
}

// ---------------- CSR fill ----------------
__global__ __launch_bounds__(256) void k_fill(const void* __restrict__ src,
                                              const void* __restrict__ dst,
                                              const int* __restrict__ flag,
                                              int* __restrict__ cursor,
                                              int* __restrict__ csr_src) {
  const bool i64 = (flag[1] != 0);
  int e = blockIdx.x * 256 + threadIdx.x;
  if (e < NE) {
    int d = geti(dst, e, i64);
    int slot = atomicAdd(&cursor[d], 1);
    csr_src[slot] = geti(src, e, i64);
  }
}

// ---------------- embed: relu(X@W+b) -> fp32 out + bf16 out-norm-scaled copy ----------------
__global__ __launch_bounds__(256) void k_embed(const void* __restrict__ featv,
                                               const void* __restrict__ Wv,
                                               const void* __restrict__ biasv,
                                               const int* __restrict__ flag,
                                               const float* __restrict__ onorm_base,
                                               float* __restrict__ out,
                                               bf16_t* __restrict__ embs, int rows) {
  __shared__ float Ws[DIM * HID];  // 32 KB
  __shared__ float bs[HID];
  const bool f32 = (flag[0] != 0);
  int t = threadIdx.x;
  if (f32) {
    const float* W = (const float*)Wv;
    for (int i = t; i < DIM * HID; i += 256) Ws[i] = W[i];
    if (t < HID) bs[t] = ((const float*)biasv)[t];
  } else {
    const bf16_t* W = (const bf16_t*)Wv;
    for (int i = t; i < DIM * HID; i += 256) Ws[i] = bf2f(W[i]);
    if (t < HID) bs[t] = bf2f(((const bf16_t*)biasv)[t]);
  }
  __syncthreads();
  int rl = t >> 4;
  int jq = t & 15;
  for (int rbase = blockIdx.x * 16; rbase < rows; rbase += gridDim.x * 16) {
    int row = rbase + rl;
    if (row >= rows) continue;
    float a0 = 0.f, a1 = 0.f, a2 = 0.f, a3 = 0.f;
    if (f32) {
      const float* fr = (const float*)featv + (size_t)row * DIM;
      for (int k0 = 0; k0 < DIM; k0 += 4) {
        float4 f4 = *(const float4*)(fr + k0);
        float fk[4] = {f4.x, f4.y, f4.z, f4.w};
#pragma unroll
        for (int kk = 0; kk < 4; ++kk) {
          const float* wr = &Ws[(k0 + kk) * HID + jq * 4];
          a0 += fk[kk] * wr[0];
          a1 += fk[kk] * wr[1];
          a2 += fk[kk] * wr[2];
          a3 += fk[kk] * wr[3];
        }
      }
    } else {
      const bf16_t* fr = (const bf16_t*)featv + (size_t)row * DIM;
      for (int k0 = 0; k0 < DIM; k0 += 8) {
        uint4 u = *(const uint4*)(fr + k0);
        unsigned int w[4] = {u.x, u.y, u.z, u.w};
#pragma unroll
        for (int kk = 0; kk < 8; ++kk) {
          unsigned short us = (unsigned short)((w[kk >> 1] >> ((kk & 1) * 16)) & 0xffffu);
          float fk = bf2f(us);
          const float* wr = &Ws[(k0 + kk) * HID + jq * 4];
          a0 += fk * wr[0];
          a1 += fk * wr[1];
          a2 += fk * wr[2];
          a3 += fk * wr[3];
        }
      }
    }
    float4 r;
    r.x = fmaxf(a0 + bs[jq * 4 + 0], 0.f);
    r.y = fmaxf(a1 + bs[jq * 4 + 1], 0.f);
    r.z = fmaxf(a2 + bs[jq * 4 + 2], 0.f);
    r.w = fmaxf(a3 + bs[jq * 4 + 3], 0.f);
    *(float4*)&out[(size_t)row * HID + jq * 4] = r;
    float sc = onorm_base[row];
    uint2 p;
    p.x = (unsigned int)f2bf(r.x * sc) | ((unsigned int)f2bf(r.y * sc) << 16);
    p.y = (unsigned int)f2bf(r.z * sc) | ((unsigned int)f2bf(r.w * sc) << 16);
    *(uint2*)&embs[(size_t)row * HID + jq * 4] = p;
  }
}

// ---------------- gather layer 1: e1s[n] = inorm[n]*onorm[n] * sum embs[src] ----------------
// one wave per dst node; 4 edges/iteration (16 lanes x 8 B each)
__global__ __launch_bounds__(256) void k_gather1(const bf16_t* __restrict__ embs,
                                                 const float* __restrict__ onorm,
                                                 const float* __restrict__ inorm,
                                                 const int* __restrict__ row_ptr,
                                                 const int* __restrict__ csr_src,
                                                 bf16_t* __restrict__ e1s) {
  int n = blockIdx.x * 4 + (threadIdx.x >> 6);
  if (n >= NN) return;
  int lane = threadIdx.x & 63;
  int g = lane >> 4, l = lane & 15;
  int beg = row_ptr[n], end = row_ptr[n + 1];
  float a0 = 0.f, a1 = 0.f, a2 = 0.f, a3 = 0.f;
  for (int e = beg + g; e < end; e += 4) {
    int s = csr_src[e];
    uint2 u = *(const uint2*)(embs + (size_t)s * HID + l * 4);
    a0 += bf2f((unsigned short)(u.x & 0xffffu));
    a1 += bf2f((unsigned short)(u.x >> 16));
    a2 += bf2f((unsigned short)(u.y & 0xffffu));
    a3 += bf2f((unsigned short)(u.y >> 16));
  }
  a0 += __shfl_xor(a0, 16); a0 += __shfl_xor(a0, 32);
  a1 += __shfl_xor(a1, 16); a1 += __shfl_xor(a1, 32);
  a2 += __shfl_xor(a2, 16); a2 += __shfl_xor(a2, 32);
  a3 += __shfl_xor(a3, 16); a3 += __shfl_xor(a3, 32);
  if (g == 0) {
    float sc = inorm[n] * onorm[n];   // pre-scale for next gather
    uint2 p;
    p.x = (unsigned int)f2bf(a0 * sc) | ((unsigned int)f2bf(a1 * sc) << 16);
    p.y = (unsigned int)f2bf(a2 * sc) | ((unsigned int)f2bf(a3 * sc) << 16);
    *(uint2*)(e1s + (size_t)n * HID + l * 4) = p;
  }
}

// ---------------- gather layer 2 + combine + side; in-place on fp32 emb0 ----------------
__global__ __launch_bounds__(256) void k_gather2c(float* __restrict__ emb0,
                                                  const bf16_t* __restrict__ e1s,
                                                  const void* __restrict__ sidev,
                                                  const int* __restrict__ flag,
                                                  const float* __restrict__ onorm,
                                                  const float* __restrict__ inorm,
                                                  const int* __restrict__ row_ptr,
                                                  const int* __restrict__ csr_src) {
  int n = blockIdx.x * 4 + (threadIdx.x >> 6);
  if (n >= NN) return;
  int lane = threadIdx.x & 63;
  int g = lane >> 4, l = lane & 15;
  int beg = row_ptr[n], end = row_ptr[n + 1];
  float a0 = 0.f, a1 = 0.f, a2 = 0.f, a3 = 0.f;
  for (int e = beg + g; e < end; e += 4) {
    int s = csr_src[e];
    uint2 u = *(const uint2*)(e1s + (size_t)s * HID + l * 4);
    a0 += bf2f((unsigned short)(u.x & 0xffffu));
    a1 += bf2f((unsigned short)(u.x >> 16));
    a2 += bf2f((unsigned short)(u.y & 0xffffu));
    a3 += bf2f((unsigned short)(u.y >> 16));
  }
  a0 += __shfl_xor(a0, 16); a0 += __shfl_xor(a0, 32);
  a1 += __shfl_xor(a1, 16); a1 += __shfl_xor(a1, 32);
  a2 += __shfl_xor(a2, 16); a2 += __shfl_xor(a2, 32);
  a3 += __shfl_xor(a3, 16); a3 += __shfl_xor(a3, 32);
  if (g == 0) {
    float inorm_n = inorm[n];
    float inv_on = 1.0f / onorm[n];     // e1 = e1s / onorm
    size_t off = (size_t)n * HID + l * 4;
    uint2 u = *(const uint2*)(e1s + off);
    float e0 = bf2f((unsigned short)(u.x & 0xffffu)) * inv_on;
    float e1v = bf2f((unsigned short)(u.x >> 16)) * inv_on;
    float e2 = bf2f((unsigned short)(u.y & 0xffffu)) * inv_on;
    float e3 = bf2f((unsigned short)(u.y >> 16)) * inv_on;
    float4 base = *(const float4*)&emb0[off];
    const float s2 = 1.f / 3.f;
    float4 v;
    v.x = base.x + 0.5f * e0 + s2 * a0 * inorm_n;
    v.y = base.y + 0.5f * e1v + s2 * a1 * inorm_n;
    v.z = base.z + 0.5f * e2 + s2 * a2 * inorm_n;
    v.w = base.w + 0.5f * e3 + s2 * a3 * inorm_n;
    if (n >= NU) {
      size_t soff = (size_t)(n - NU) * HID + l * 4;
      if (flag[0] != 0) {
        float4 s4 = *(const float4*)((const float*)sidev + soff);
        v.x += s4.x; v.y += s4.y; v.z += s4.z; v.w += s4.w;
      } else {
        const bf16_t* sp = (const bf16_t*)sidev + soff;
        v.x += bf2f(sp[0]); v.y += bf2f(sp[1]); v.z += bf2f(sp[2]); v.w += bf2f(sp[3]);
      }
    }
    *(float4*)&emb0[off] = v;
  }
}

// ---------------- decode: 2 pair-rows per thread, 32 cols each ----------------
__global__ __launch_bounds__(256) void k_decode(const float* __restrict__ emb,
                                                const void* __restrict__ W1v,
                                                const void* __restrict__ b1v,
                                                const void* __restrict__ W2v,
                                                const void* __restrict__ Tfv,
                                                const void* __restrict__ Tcfv,
                                                const int* __restrict__ flag,
                                                const void* __restrict__ userId,
                                                const void* __restrict__ posId,
                                                const void* __restrict__ negId,
                                                float* __restrict__ out_lf,
                                                float* __restrict__ out_lcf) {
  __shared__ float W1s[129 * HID];  // 33 KB
  __shared__ float b1s[HID];
  __shared__ float W2s[HID];
  const bool f32 = (flag[0] != 0);
  const bool i64 = (flag[1] != 0);
  int t = threadIdx.x;
  if (f32) {
    const float* W1 = (const float*)W1v;
    for (int i = t; i < 129 * HID; i += 256) W1s[i] = W1[i];
    if (t < HID) {
      b1s[t] = ((const float*)b1v)[t];
      W2s[t] = ((const float*)W2v)[t];
    }
  } else {
    const bf16_t* W1 = (const bf16_t*)W1v;
    for (int i = t; i < 129 * HID; i += 256) W1s[i] = bf2f(W1[i]);
    if (t < HID) {
      b1s[t] = bf2f(((const bf16_t*)b1v)[t]);
      W2s[t] = bf2f(((const bf16_t*)W2v)[t]);
    }
  }
  __syncthreads();
  int prl = t >> 1;
  int half = t & 1;
  int jb = half * 32;
  int prA = blockIdx.x * 256 + prl;       // rows prA and prA+128
  int prB = prA + 128;
  bool vB = (prB < 2 * NP);
  if (prA >= 2 * NP) return;
  int prBc = vB ? prB : prA;

  int pidA = prA < NP ? prA : prA - NP;
  int pidB = prBc < NP ? prBc : prBc - NP;
  int uidA = geti(userId, pidA, i64);
  int uidB = geti(userId, pidB, i64);
  int iidA = (prA < NP) ? geti(posId, pidA, i64) : geti(negId, pidA, i64);
  int iidB = (prBc < NP) ? geti(posId, pidB, i64) : geti(negId, pidB, i64);
  const float* urA = emb + (size_t)uidA * HID;
  const float* irA = emb + (size_t)(NU + iidA) * HID;
  const float* urB = emb + (size_t)uidB * HID;
  const float* irB = emb + (size_t)(NU + iidB) * HID;

  float accA[32], accB[32];
#pragma unroll
  for (int j = 0; j < 32; ++j) { accA[j] = b1s[jb + j]; accB[j] = b1s[jb + j]; }

  for (int pass = 0; pass < 2; ++pass) {
    const float* zrA = pass ? irA : urA;
    const float* zrB = pass ? irB : urB;
    const float* Wbase = &W1s[pass * 64 * HID];
    for (int k0 = 0; k0 < HID; k0 += 4) {
      float4 zA = *(const float4*)(zrA + k0);
      float4 zB = *(const float4*)(zrB + k0);
      float zkA[4] = {zA.x, zA.y, zA.z, zA.w};
      float zkB[4] = {zB.x, zB.y, zB.z, zB.w};
#pragma unroll
      for (int kk = 0; kk < 4; ++kk) {
        const float* wr = &Wbase[(size_t)(k0 + kk) * HID + jb];
#pragma unroll
        for (int q = 0; q < 8; ++q) {
          float4 w = *(const float4*)(wr + q * 4);
          accA[q * 4 + 0] += zkA[kk] * w.x;
          accA[q * 4 + 1] += zkA[kk] * w.y;
          accA[q * 4 + 2] += zkA[kk] * w.z;
          accA[q * 4 + 3] += zkA[kk] * w.w;
          accB[q * 4 + 0] += zkB[kk] * w.x;
          accB[q * 4 + 1] += zkB[kk] * w.y;
          accB[q * 4 + 2] += zkB[kk] * w.z;
          accB[q * 4 + 3] += zkB[kk] * w.w;
        }
      }
    }
  }

  const float* wlast = &W1s[128 * HID + jb];
#pragma unroll
  for (int r = 0; r < 2; ++r) {
    int pr = r ? prB : prA;
    if (r && !vB) break;
    float* acc = r ? accB : accA;
    float tf, tcf;
    if (f32) {
      tf = ((const float*)Tfv)[pr];
      tcf = ((const float*)Tcfv)[pr];
    } else {
      tf = bf2f(((const bf16_t*)Tfv)[pr]);
      tcf = bf2f(((const bf16_t*)Tcfv)[pr]);
    }
    float sf = 0.f, scf = 0.f;
#pragma unroll
    for (int j = 0; j < 32; ++j) {
      float wl = wlast[j];
      float w2 = W2s[jb + j];
      float bfv = acc[j] + tf * wl;
      float bcv = acc[j] + tcf * wl;
      float hf = bfv > 0.f ? bfv : (expf(bfv) - 1.f);
      float hc = bcv > 0.f ? bcv : (expf(bcv) - 1.f);
      sf += hf * w2;
      scf += hc * w2;
    }
    sf += __shfl_xor(sf, 1);
    scf += __shfl_xor(scf, 1);
    if (half == 0) {
      out_lf[pr] = sf;
      out_lcf[pr] = scf;
    }
  }
}

extern "C" void kernel_launch(void* const* d_in, const int* in_sizes, int n_in,
                              void* d_out, int out_size, void* d_ws, size_t ws_size,
                              hipStream_t stream) {
  (void)in_sizes; (void)n_in; (void)out_size;
  const void* user_f = d_in[0];
  const void* item_f = d_in[1];
  const void* side   = d_in[2];
  const void* Tf     = d_in[3];
  const void* Tcf    = d_in[4];
  const void* Wu     = d_in[5];
  const void* bu     = d_in[6];
  const void* Wi     = d_in[7];
  const void* bi     = d_in[8];
  const void* W1     = d_in[9];
  const void* b1     = d_in[10];
  const void* W2     = d_in[11];
  const void* esrc   = d_in[12];
  const void* edst   = d_in[13];
  const void* userId = d_in[14];
  const void* posId  = d_in[15];
  const void* negId  = d_in[16];

  // workspace layout — total 34,401,280 B (r3 ran identically at this size: safe)
  const size_t WS_NEEDED = 34401280;
  if (ws_size < WS_NEEDED) return;

  char* ws = (char*)d_ws;
  int*   deg_out = (int*)(ws + 0);
  int*   deg_in  = (int*)(ws + 400000);
  float* onorm   = (float*)(ws + 800000);
  float* inorm   = (float*)(ws + 1200000);
  int*   row_ptr = (int*)(ws + 1600000);
  int*   cursor  = (int*)(ws + 2000128);
  int*   bsums   = (int*)(ws + 2400128);
  int*   boffs   = (int*)(ws + 2400640);
  int*   flag    = (int*)(ws + 2401152);
  int*   csr_src = (int*)(ws + 2401280);       // 6.4 MB
  bf16_t* embs   = (bf16_t*)(ws + 8801280);    // 12.8 MB: emb0*onorm, bf16
  bf16_t* e1s    = (bf16_t*)(ws + 21601280);   // 12.8 MB: e1*onorm, bf16 -> 34,401,280

  float* out     = (float*)d_out;
  float* emb0    = out;                        // fp32 embeddings staged in output region
  float* out_lf  = out + (size_t)NN * HID;
  float* out_lcf = out_lf + 2 * NP;

  hipMemsetAsync(deg_out, 0, 800000, stream);

  k_detect<<<1, 64, 0, stream>>>((const bf16_t*)user_f, (const int*)esrc, flag);
  k_degrees<<<(NE + 255) / 256, 256, 0, stream>>>(esrc, edst, flag, deg_out, deg_in);
  k_norms<<<(NN + 255) / 256, 256, 0, stream>>>(deg_out, deg_in, onorm, inorm);
  k_scan1<<<98, 256, 0, stream>>>(deg_in, bsums, NN);
  k_scan2<<<1, 128, 0, stream>>>(bsums, boffs, 98);
  k_scan3<<<98, 256, 0, stream>>>(deg_in, boffs, row_ptr, cursor, NN);
  k_fill<<<(NE + 255) / 256, 256, 0, stream>>>(esrc, edst, flag, cursor, csr_src);
  k_embed<<<256, 256, 0, stream>>>(user_f, Wu, bu, flag, onorm, emb0, embs, NU);
  k_embed<<<256, 256, 0, stream>>>(item_f, Wi, bi, flag, onorm + NU,
                                   emb0 + (size_t)NU * HID, embs + (size_t)NU * HID, NI);
  k_gather1<<<NN / 4, 256, 0, stream>>>(embs, onorm, inorm, row_ptr, csr_src, e1s);
  k_gather2c<<<NN / 4, 256, 0, stream>>>(emb0, e1s, side, flag, onorm, inorm, row_ptr, csr_src);
  k_decode<<<(2 * NP + 255) / 256, 256, 0, stream>>>(emb0, W1, b1, W2, Tf, Tcf, flag,
                                                     userId, posId, negId, out_lf, out_lcf);
}

// Round 8
// 623.332 us; speedup vs baseline: 1.4984x; 1.1962x over previous
//
#include <hip/hip_runtime.h>

#define NU 50000
#define NI 50000
#define NN 100000
#define NE 1600000
#define NP 200000
#define DIM 128
#define HID 64

typedef unsigned short bf16_t;
typedef __attribute__((ext_vector_type(8))) short short8;
typedef __attribute__((ext_vector_type(4))) float f32x4;

__device__ __forceinline__ float bf2f(unsigned short u) {
  union { unsigned int i; float f; } c; c.i = ((unsigned int)u) << 16; return c.f;
}
__device__ __forceinline__ unsigned short f2bf(float f) {
  union { float f; unsigned int i; } c; c.f = f;
  unsigned int i = c.i;
  i += 0x7fffu + ((i >> 16) & 1u);   // RNE
  return (unsigned short)(i >> 16);
}
__device__ __forceinline__ int geti(const void* p, int i, bool i64) {
  return i64 ? (int)((const long long*)p)[i] : ((const int*)p)[i];
}

// ---------------- dtype probes ----------------
__global__ __launch_bounds__(64) void k_detect(const bf16_t* __restrict__ uf,
                                               const int* __restrict__ ei,
                                               int* __restrict__ flag) {
  int lane = threadIdx.x;
  float m = 0.f;
  for (int i = lane; i < 4096; i += 64) {
    float v = fabsf(bf2f(uf[i]));
    if (v < 3e38f) m = fmaxf(m, v);
  }
  int cnt = 0;
  for (int i = lane; i < 4096; i += 64) {
    if (ei[2 * i + 1] == 0) cnt++;
  }
  for (int off = 32; off > 0; off >>= 1) {
    m = fmaxf(m, __shfl_xor(m, off));
    cnt += __shfl_xor(cnt, off);
  }
  if (lane == 0) {
    flag[0] = (m > 100.f) ? 1 : 0;   // fp32 floats
    flag[1] = (cnt > 2048) ? 1 : 0;  // int64 ints
  }
}

// ---------------- degrees ----------------
__global__ __launch_bounds__(256) void k_degrees(const void* __restrict__ src,
                                                 const void* __restrict__ dst,
                                                 const int* __restrict__ flag,
                                                 int* __restrict__ dout,
                                                 int* __restrict__ din) {
  const bool i64 = (flag[1] != 0);
  int e = blockIdx.x * 256 + threadIdx.x;
  if (e < NE) {
    atomicAdd(&dout[geti(src, e, i64)], 1);
    atomicAdd(&din[geti(dst, e, i64)], 1);
  }
}

// ---------------- norms ----------------
__global__ __launch_bounds__(256) void k_norms(const int* __restrict__ dout,
                                               const int* __restrict__ din,
                                               float* __restrict__ onorm,
                                               float* __restrict__ inorm) {
  int n = blockIdx.x * 256 + threadIdx.x;
  if (n < NN) {
    int o = dout[n] > 1 ? dout[n] : 1;
    int in_ = din[n] > 1 ? din[n] : 1;
    onorm[n] = rsqrtf((float)o);
    inorm[n] = rsqrtf((float)in_);
  }
}

// ---------------- scan ----------------
__global__ __launch_bounds__(256) void k_scan1(const int* __restrict__ in,
                                               int* __restrict__ bsums, int n) {
  __shared__ int sh[256];
  int t = threadIdx.x;
  int base = blockIdx.x * 1024 + t * 4;
  int s = 0;
#pragma unroll
  for (int i = 0; i < 4; ++i)
    if (base + i < n) s += in[base + i];
  sh[t] = s;
  __syncthreads();
  for (int off = 128; off > 0; off >>= 1) {
    if (t < off) sh[t] += sh[t + off];
    __syncthreads();
  }
  if (t == 0) bsums[blockIdx.x] = sh[0];
}

__global__ __launch_bounds__(128) void k_scan2(const int* __restrict__ bsums,
                                               int* __restrict__ boffs, int nb) {
  __shared__ int sh[128];
  int t = threadIdx.x;
  int own = (t < nb) ? bsums[t] : 0;
  sh[t] = own;
  __syncthreads();
  for (int off = 1; off < 128; off <<= 1) {
    int add = (t >= off) ? sh[t - off] : 0;
    __syncthreads();
    sh[t] += add;
    __syncthreads();
  }
  if (t < nb) boffs[t] = sh[t] - own;
}

__global__ __launch_bounds__(256) void k_scan3(const int* __restrict__ in,
                                               const int* __restrict__ boffs,
                                               int* __restrict__ row_ptr,
                                               int* __restrict__ cursor, int n) {
  __shared__ int sh[256];
  int t = threadIdx.x;
  int base = blockIdx.x * 1024 + t * 4;
  int v[4];
  int s = 0;
#pragma unroll
  for (int i = 0; i < 4; ++i) {
    v[i] = (base + i < n) ? in[base + i] : 0;
    s += v[i];
  }
  sh[t] = s;
  __syncthreads();
  for (int off = 1; off < 256; off <<= 1) {
    int add = (t >= off) ? sh[t - off] : 0;
    __syncthreads();
    sh[t] += add;
    __syncthreads();
  }
  int excl = boffs[blockIdx.x] + sh[t] - s;
#pragma unroll
  for (int i = 0; i < 4; ++i) {
    if (base + i < n) {
      row_ptr[base + i] = excl;
      cursor[base + i] = excl;
      excl += v[i];
    }
  }
  if (blockIdx.x == 0 && t == 0) row_ptr[n] = NE;
}

// ---------------- CSR fill, XCD-affine dst partitioning ----------------
// range r = blockIdx%8 (round-robin block->XCD): all writes to csr slice r come
// from one XCD -> full cache lines assemble in its L2 (kills the 16x write amp).
#define FILL_CHUNKS 128
__global__ __launch_bounds__(256) void k_fill(const void* __restrict__ src,
                                              const void* __restrict__ dst,
                                              const int* __restrict__ flag,
                                              int* __restrict__ cursor,
                                              int* __restrict__ csr_src) {
  const bool i64 = (flag[1] != 0);
  int r = blockIdx.x & 7;            // dst range (XCD-affine)
  int c = blockIdx.x >> 3;           // edge chunk
  int lo = r * (NN / 8), hi = lo + (NN / 8);
  int ebeg = c * (NE / FILL_CHUNKS);
  int eend = ebeg + (NE / FILL_CHUNKS);
  for (int e = ebeg + threadIdx.x; e < eend; e += 256) {
    int d = geti(dst, e, i64);
    if (d >= lo && d < hi) {
      int slot = atomicAdd(&cursor[d], 1);
      csr_src[slot] = geti(src, e, i64);
    }
  }
}

// ---------------- embed: relu(X@W+b) -> fp32 out + bf16 out-norm-scaled copy ----------------
__global__ __launch_bounds__(256) void k_embed(const void* __restrict__ featv,
                                               const void* __restrict__ Wv,
                                               const void* __restrict__ biasv,
                                               const int* __restrict__ flag,
                                               const float* __restrict__ onorm_base,
                                               float* __restrict__ out,
                                               bf16_t* __restrict__ embs, int rows) {
  __shared__ float Ws[DIM * HID];  // 32 KB
  __shared__ float bs[HID];
  const bool f32 = (flag[0] != 0);
  int t = threadIdx.x;
  if (f32) {
    const float* W = (const float*)Wv;
    for (int i = t; i < DIM * HID; i += 256) Ws[i] = W[i];
    if (t < HID) bs[t] = ((const float*)biasv)[t];
  } else {
    const bf16_t* W = (const bf16_t*)Wv;
    for (int i = t; i < DIM * HID; i += 256) Ws[i] = bf2f(W[i]);
    if (t < HID) bs[t] = bf2f(((const bf16_t*)biasv)[t]);
  }
  __syncthreads();
  int rl = t >> 4;
  int jq = t & 15;
  for (int rbase = blockIdx.x * 16; rbase < rows; rbase += gridDim.x * 16) {
    int row = rbase + rl;
    if (row >= rows) continue;
    float a0 = 0.f, a1 = 0.f, a2 = 0.f, a3 = 0.f;
    if (f32) {
      const float* fr = (const float*)featv + (size_t)row * DIM;
      for (int k0 = 0; k0 < DIM; k0 += 4) {
        float4 f4 = *(const float4*)(fr + k0);
        float fk[4] = {f4.x, f4.y, f4.z, f4.w};
#pragma unroll
        for (int kk = 0; kk < 4; ++kk) {
          const float* wr = &Ws[(k0 + kk) * HID + jq * 4];
          a0 += fk[kk] * wr[0];
          a1 += fk[kk] * wr[1];
          a2 += fk[kk] * wr[2];
          a3 += fk[kk] * wr[3];
        }
      }
    } else {
      const bf16_t* fr = (const bf16_t*)featv + (size_t)row * DIM;
      for (int k0 = 0; k0 < DIM; k0 += 8) {
        uint4 u = *(const uint4*)(fr + k0);
        unsigned int w[4] = {u.x, u.y, u.z, u.w};
#pragma unroll
        for (int kk = 0; kk < 8; ++kk) {
          unsigned short us = (unsigned short)((w[kk >> 1] >> ((kk & 1) * 16)) & 0xffffu);
          float fk = bf2f(us);
          const float* wr = &Ws[(k0 + kk) * HID + jq * 4];
          a0 += fk * wr[0];
          a1 += fk * wr[1];
          a2 += fk * wr[2];
          a3 += fk * wr[3];
        }
      }
    }
    float4 r;
    r.x = fmaxf(a0 + bs[jq * 4 + 0], 0.f);
    r.y = fmaxf(a1 + bs[jq * 4 + 1], 0.f);
    r.z = fmaxf(a2 + bs[jq * 4 + 2], 0.f);
    r.w = fmaxf(a3 + bs[jq * 4 + 3], 0.f);
    *(float4*)&out[(size_t)row * HID + jq * 4] = r;
    float sc = onorm_base[row];
    uint2 p;
    p.x = (unsigned int)f2bf(r.x * sc) | ((unsigned int)f2bf(r.y * sc) << 16);
    p.y = (unsigned int)f2bf(r.z * sc) | ((unsigned int)f2bf(r.w * sc) << 16);
    *(uint2*)&embs[(size_t)row * HID + jq * 4] = p;
  }
}

// ---------------- gather layer 1 ----------------
__global__ __launch_bounds__(256) void k_gather1(const bf16_t* __restrict__ embs,
                                                 const float* __restrict__ onorm,
                                                 const float* __restrict__ inorm,
                                                 const int* __restrict__ row_ptr,
                                                 const int* __restrict__ csr_src,
                                                 bf16_t* __restrict__ e1s) {
  int n = blockIdx.x * 4 + (threadIdx.x >> 6);
  if (n >= NN) return;
  int lane = threadIdx.x & 63;
  int g = lane >> 4, l = lane & 15;
  int beg = row_ptr[n], end = row_ptr[n + 1];
  float a0 = 0.f, a1 = 0.f, a2 = 0.f, a3 = 0.f;
  for (int e = beg + g; e < end; e += 4) {
    int s = csr_src[e];
    uint2 u = *(const uint2*)(embs + (size_t)s * HID + l * 4);
    a0 += bf2f((unsigned short)(u.x & 0xffffu));
    a1 += bf2f((unsigned short)(u.x >> 16));
    a2 += bf2f((unsigned short)(u.y & 0xffffu));
    a3 += bf2f((unsigned short)(u.y >> 16));
  }
  a0 += __shfl_xor(a0, 16); a0 += __shfl_xor(a0, 32);
  a1 += __shfl_xor(a1, 16); a1 += __shfl_xor(a1, 32);
  a2 += __shfl_xor(a2, 16); a2 += __shfl_xor(a2, 32);
  a3 += __shfl_xor(a3, 16); a3 += __shfl_xor(a3, 32);
  if (g == 0) {
    float sc = inorm[n] * onorm[n];   // pre-scale for next gather
    uint2 p;
    p.x = (unsigned int)f2bf(a0 * sc) | ((unsigned int)f2bf(a1 * sc) << 16);
    p.y = (unsigned int)f2bf(a2 * sc) | ((unsigned int)f2bf(a3 * sc) << 16);
    *(uint2*)(e1s + (size_t)n * HID + l * 4) = p;
  }
}

// ---------------- gather layer 2 + combine + side; writes fp32 emb0 AND bf16 fin_bf ----------------
__global__ __launch_bounds__(256) void k_gather2c(float* __restrict__ emb0,
                                                  const bf16_t* __restrict__ e1s,
                                                  const void* __restrict__ sidev,
                                                  const int* __restrict__ flag,
                                                  const float* __restrict__ onorm,
                                                  const float* __restrict__ inorm,
                                                  const int* __restrict__ row_ptr,
                                                  const int* __restrict__ csr_src,
                                                  bf16_t* __restrict__ fin_bf) {
  int n = blockIdx.x * 4 + (threadIdx.x >> 6);
  if (n >= NN) return;
  int lane = threadIdx.x & 63;
  int g = lane >> 4, l = lane & 15;
  int beg = row_ptr[n], end = row_ptr[n + 1];
  float a0 = 0.f, a1 = 0.f, a2 = 0.f, a3 = 0.f;
  for (int e = beg + g; e < end; e += 4) {
    int s = csr_src[e];
    uint2 u = *(const uint2*)(e1s + (size_t)s * HID + l * 4);
    a0 += bf2f((unsigned short)(u.x & 0xffffu));
    a1 += bf2f((unsigned short)(u.x >> 16));
    a2 += bf2f((unsigned short)(u.y & 0xffffu));
    a3 += bf2f((unsigned short)(u.y >> 16));
  }
  a0 += __shfl_xor(a0, 16); a0 += __shfl_xor(a0, 32);
  a1 += __shfl_xor(a1, 16); a1 += __shfl_xor(a1, 32);
  a2 += __shfl_xor(a2, 16); a2 += __shfl_xor(a2, 32);
  a3 += __shfl_xor(a3, 16); a3 += __shfl_xor(a3, 32);
  if (g == 0) {
    float inorm_n = inorm[n];
    float inv_on = 1.0f / onorm[n];     // e1 = e1s / onorm
    size_t off = (size_t)n * HID + l * 4;
    uint2 u = *(const uint2*)(e1s + off);
    float e0 = bf2f((unsigned short)(u.x & 0xffffu)) * inv_on;
    float e1v = bf2f((unsigned short)(u.x >> 16)) * inv_on;
    float e2 = bf2f((unsigned short)(u.y & 0xffffu)) * inv_on;
    float e3 = bf2f((unsigned short)(u.y >> 16)) * inv_on;
    float4 base = *(const float4*)&emb0[off];
    const float s2 = 1.f / 3.f;
    float4 v;
    v.x = base.x + 0.5f * e0 + s2 * a0 * inorm_n;
    v.y = base.y + 0.5f * e1v + s2 * a1 * inorm_n;
    v.z = base.z + 0.5f * e2 + s2 * a2 * inorm_n;
    v.w = base.w + 0.5f * e3 + s2 * a3 * inorm_n;
    if (n >= NU) {
      size_t soff = (size_t)(n - NU) * HID + l * 4;
      if (flag[0] != 0) {
        float4 s4 = *(const float4*)((const float*)sidev + soff);
        v.x += s4.x; v.y += s4.y; v.z += s4.z; v.w += s4.w;
      } else {
        const bf16_t* sp = (const bf16_t*)sidev + soff;
        v.x += bf2f(sp[0]); v.y += bf2f(sp[1]); v.z += bf2f(sp[2]); v.w += bf2f(sp[3]);
      }
    }
    *(float4*)&emb0[off] = v;
    uint2 pb;
    pb.x = (unsigned int)f2bf(v.x) | ((unsigned int)f2bf(v.y) << 16);
    pb.y = (unsigned int)f2bf(v.z) | ((unsigned int)f2bf(v.w) << 16);
    *(uint2*)(fin_bf + off) = pb;
  }
}

// ---------------- decode via MFMA 16x16x32 bf16 ----------------
// one wave = 16 pair-rows; K=128 ([u|i]); T column + b1 + ELU + W2-dot in epilogue.
__global__ __launch_bounds__(256) void k_decode(const bf16_t* __restrict__ zb,  // fin_bf
                                                const void* __restrict__ W1v,
                                                const void* __restrict__ b1v,
                                                const void* __restrict__ W2v,
                                                const void* __restrict__ Tfv,
                                                const void* __restrict__ Tcfv,
                                                const int* __restrict__ flag,
                                                const void* __restrict__ userId,
                                                const void* __restrict__ posId,
                                                const void* __restrict__ negId,
                                                float* __restrict__ out_lf,
                                                float* __restrict__ out_lcf) {
  __shared__ bf16_t W1b[128 * 65];   // padded rows (65) to dodge LDS bank conflicts
  __shared__ float wlast[HID], b1s[HID], W2s[HID];
  const bool f32 = (flag[0] != 0);
  const bool i64 = (flag[1] != 0);
  int t = threadIdx.x;
  if (f32) {
    const float* W1 = (const float*)W1v;
    for (int i = t; i < 128 * 64; i += 256) W1b[(i >> 6) * 65 + (i & 63)] = f2bf(W1[i]);
    if (t < HID) {
      wlast[t] = W1[128 * 64 + t];
      b1s[t] = ((const float*)b1v)[t];
      W2s[t] = ((const float*)W2v)[t];
    }
  } else {
    const bf16_t* W1 = (const bf16_t*)W1v;
    for (int i = t; i < 128 * 64; i += 256) W1b[(i >> 6) * 65 + (i & 63)] = W1[i];
    if (t < HID) {
      wlast[t] = bf2f(W1[128 * 64 + t]);
      b1s[t] = bf2f(((const bf16_t*)b1v)[t]);
      W2s[t] = bf2f(((const bf16_t*)W2v)[t]);
    }
  }
  __syncthreads();
  int wv = t >> 6;
  int lane = t & 63;
  int m = lane & 15;     // A row within tile / B col
  int q = lane >> 4;     // k-subchunk
  // B fragments: Bf[c][nt][j] = W1[k = c*32+q*8+j][n = nt*16+m]  (staged once per wave)
  short8 Bf[4][4];
#pragma unroll
  for (int c = 0; c < 4; ++c)
#pragma unroll
    for (int nt = 0; nt < 4; ++nt)
#pragma unroll
      for (int j = 0; j < 8; ++j)
        Bf[c][nt][j] = (short)W1b[(c * 32 + q * 8 + j) * 65 + nt * 16 + m];

  const int tiles = (2 * NP) / 16;  // 25000
  for (int tile = blockIdx.x * 4 + wv; tile < tiles; tile += gridDim.x * 4) {
    int pr = tile * 16 + m;
    int pid = pr < NP ? pr : pr - NP;
    int uid = geti(userId, pid, i64);
    int iid = (pr < NP) ? geti(posId, pid, i64) : geti(negId, pid, i64);
    const bf16_t* ur = zb + (size_t)uid * HID;
    const bf16_t* ir = zb + (size_t)(NU + iid) * HID;
    short8 a0 = *(const short8*)(ur + q * 8);
    short8 a1 = *(const short8*)(ur + 32 + q * 8);
    short8 a2 = *(const short8*)(ir + q * 8);
    short8 a3 = *(const short8*)(ir + 32 + q * 8);
    f32x4 acc[4];
#pragma unroll
    for (int nt = 0; nt < 4; ++nt) acc[nt] = (f32x4)(0.f);
#pragma unroll
    for (int nt = 0; nt < 4; ++nt) {
      acc[nt] = __builtin_amdgcn_mfma_f32_16x16x32_bf16(a0, Bf[0][nt], acc[nt], 0, 0, 0);
      acc[nt] = __builtin_amdgcn_mfma_f32_16x16x32_bf16(a1, Bf[1][nt], acc[nt], 0, 0, 0);
      acc[nt] = __builtin_amdgcn_mfma_f32_16x16x32_bf16(a2, Bf[2][nt], acc[nt], 0, 0, 0);
      acc[nt] = __builtin_amdgcn_mfma_f32_16x16x32_bf16(a3, Bf[3][nt], acc[nt], 0, 0, 0);
    }
    // epilogue: lane holds D[row=4q+r][n=nt*16+m]
    float tfr[4], tcfr[4];
    int rbase = tile * 16 + q * 4;
    if (f32) {
      float4 t4 = *(const float4*)((const float*)Tfv + rbase);
      float4 c4 = *(const float4*)((const float*)Tcfv + rbase);
      tfr[0] = t4.x; tfr[1] = t4.y; tfr[2] = t4.z; tfr[3] = t4.w;
      tcfr[0] = c4.x; tcfr[1] = c4.y; tcfr[2] = c4.z; tcfr[3] = c4.w;
    } else {
      const bf16_t* tp = (const bf16_t*)Tfv + rbase;
      const bf16_t* cp = (const bf16_t*)Tcfv + rbase;
#pragma unroll
      for (int r = 0; r < 4; ++r) { tfr[r] = bf2f(tp[r]); tcfr[r] = bf2f(cp[r]); }
    }
#pragma unroll
    for (int r = 0; r < 4; ++r) {
      float sf = 0.f, scf = 0.f;
#pragma unroll
      for (int nt = 0; nt < 4; ++nt) {
        int n = nt * 16 + m;
        float x = acc[nt][r] + b1s[n];
        float wl = wlast[n];
        float w2 = W2s[n];
        float bfv = x + tfr[r] * wl;
        float bcv = x + tcfr[r] * wl;
        float hf = bfv > 0.f ? bfv : (__expf(bfv) - 1.f);
        float hc = bcv > 0.f ? bcv : (__expf(bcv) - 1.f);
        sf += hf * w2;
        scf += hc * w2;
      }
      sf += __shfl_xor(sf, 1); scf += __shfl_xor(scf, 1);
      sf += __shfl_xor(sf, 2); scf += __shfl_xor(scf, 2);
      sf += __shfl_xor(sf, 4); scf += __shfl_xor(scf, 4);
      sf += __shfl_xor(sf, 8); scf += __shfl_xor(scf, 8);
      if (m == 0) {
        int pr2 = rbase + r;
        out_lf[pr2] = sf;
        out_lcf[pr2] = scf;
      }
    }
  }
}

extern "C" void kernel_launch(void* const* d_in, const int* in_sizes, int n_in,
                              void* d_out, int out_size, void* d_ws, size_t ws_size,
                              hipStream_t stream) {
  (void)in_sizes; (void)n_in; (void)out_size;
  const void* user_f = d_in[0];
  const void* item_f = d_in[1];
  const void* side   = d_in[2];
  const void* Tf     = d_in[3];
  const void* Tcf    = d_in[4];
  const void* Wu     = d_in[5];
  const void* bu     = d_in[6];
  const void* Wi     = d_in[7];
  const void* bi     = d_in[8];
  const void* W1     = d_in[9];
  const void* b1     = d_in[10];
  const void* W2     = d_in[11];
  const void* esrc   = d_in[12];
  const void* edst   = d_in[13];
  const void* userId = d_in[14];
  const void* posId  = d_in[15];
  const void* negId  = d_in[16];

  const size_t WS_NEEDED = 34401280;
  if (ws_size < WS_NEEDED) return;

  char* ws = (char*)d_ws;
  int*   deg_out = (int*)(ws + 0);
  int*   deg_in  = (int*)(ws + 400000);
  float* onorm   = (float*)(ws + 800000);
  float* inorm   = (float*)(ws + 1200000);
  int*   row_ptr = (int*)(ws + 1600000);
  int*   cursor  = (int*)(ws + 2000128);
  int*   bsums   = (int*)(ws + 2400128);
  int*   boffs   = (int*)(ws + 2400640);
  int*   flag    = (int*)(ws + 2401152);
  int*   csr_src = (int*)(ws + 2401280);       // 6.4 MB
  bf16_t* embs   = (bf16_t*)(ws + 8801280);    // 12.8 MB: emb0*onorm bf16; later reused as fin_bf
  bf16_t* e1s    = (bf16_t*)(ws + 21601280);   // 12.8 MB: e1*onorm bf16
  bf16_t* fin_bf = embs;                       // embs dead after k_gather1 (stream-ordered)

  float* out     = (float*)d_out;
  float* emb0    = out;
  float* out_lf  = out + (size_t)NN * HID;
  float* out_lcf = out_lf + 2 * NP;

  hipMemsetAsync(deg_out, 0, 800000, stream);

  k_detect<<<1, 64, 0, stream>>>((const bf16_t*)user_f, (const int*)esrc, flag);
  k_degrees<<<(NE + 255) / 256, 256, 0, stream>>>(esrc, edst, flag, deg_out, deg_in);
  k_norms<<<(NN + 255) / 256, 256, 0, stream>>>(deg_out, deg_in, onorm, inorm);
  k_scan1<<<98, 256, 0, stream>>>(deg_in, bsums, NN);
  k_scan2<<<1, 128, 0, stream>>>(bsums, boffs, 98);
  k_scan3<<<98, 256, 0, stream>>>(deg_in, boffs, row_ptr, cursor, NN);
  k_fill<<<8 * FILL_CHUNKS, 256, 0, stream>>>(esrc, edst, flag, cursor, csr_src);
  k_embed<<<256, 256, 0, stream>>>(user_f, Wu, bu, flag, onorm, emb0, embs, NU);
  k_embed<<<256, 256, 0, stream>>>(item_f, Wi, bi, flag, onorm + NU,
                                   emb0 + (size_t)NU * HID, embs + (size_t)NU * HID, NI);
  k_gather1<<<NN / 4, 256, 0, stream>>>(embs, onorm, inorm, row_ptr, csr_src, e1s);
  k_gather2c<<<NN / 4, 256, 0, stream>>>(emb0, e1s, side, flag, onorm, inorm, row_ptr,
                                         csr_src, fin_bf);
  k_decode<<<1024, 256, 0, stream>>>(fin_bf, W1, b1, W2, Tf, Tcf, flag,
                                     userId, posId, negId, out_lf, out_lcf);
}